// Round 1
// baseline (436.338 us; speedup 1.0000x reference)
//
#include <hip/hip_runtime.h>
#include <cstdint>

#define NB 256
#define NF 1024
#define NDOF 64
#define NCLS 1000
#define CTILE 64
#define FGROUP 32
#define FCHUNK 2
#define NCHUNK (FGROUP / FCHUNK)
#define FSTRIDE 4161            /* dwords per f-slot: 64 rows * (64+1 pad) + 1 */
#define WLDS_DW (FCHUNK * FSTRIDE)

// Phase 1: per (b, f) compute the sparse hat-basis coefficients.
// meta float4 per (f-pair, b): {wA(f0), wB(f0), wA(f1), wB(f1)}
// wA = (mx-mn)*lam1 (vertex t), wB = (mx-mn)*lam0 (vertex t+1),
// t packed into wA's low 6 mantissa bits (<=63 ulp perturbation).
// Out-of-range sample: wA = wB = 0 exactly, t = 0.
__global__ __launch_bounds__(256) void lagr_meta(
    const float* __restrict__ x, const float* __restrict__ mnp,
    const float* __restrict__ mxp, float2* __restrict__ meta)
{
    int f = blockIdx.x;       // one f per block
    int b = threadIdx.x;      // 256 b's
    float mn = mnp[0], mx = mxp[0];
    float scale = mx - mn;
    float xv = x[b * NF + f];
    float xn = (xv - mn) / scale;
    const float h = 1.0f / 63.0f;     // match reference: s = xn / h
    float s = xn / h;
    float wA = 0.0f, wB = 0.0f;
    uint32_t t = 0u;
    if (s >= 0.0f && s <= 63.0f) {
        float tf = floorf(s);
        if (tf > 62.0f) tf = 62.0f;
        t  = (uint32_t)tf;
        wA = scale * (tf + 1.0f - s);
        wB = scale * (s - tf);
    }
    uint32_t bits = (__float_as_uint(wA) & ~63u) | t;
    float2 v = make_float2(__uint_as_float(bits), wB);
    meta[((size_t)(f >> 1) * NB + b) * 2 + (f & 1)] = v;
}

// Phase 2: stream W once; LDS-transposed tile gather; fold bias from row sums.
// Block: 256 threads (4 waves). blockIdx.y -> 64-class tile, blockIdx.x -> 32-f group.
// Wave w handles b in [64w, 64w+64); lane = c_local. acc[64] in VGPRs.
__global__ __launch_bounds__(256, 2) void lagr_main(
    const float4* __restrict__ meta4, const float* __restrict__ W,
    const float* __restrict__ mnp, float* __restrict__ out)
{
    __shared__ float w_lds[WLDS_DW + 64];   // + 64 floats of per-class bias

    int tid  = threadIdx.x;
    int lane = tid & 63;
    int wave = tid >> 6;
    int c0 = blockIdx.y * CTILE;
    int f0 = blockIdx.x * FGROUP;

    // staging roles: 4 threads per class row
    int cst   = tid >> 2;
    int g     = tid & 3;
    int fl_st = g >> 1;          // which f of the chunk
    int half  = g & 1;           // which 32-column half
    int crow = c0 + cst;
    if (crow > NCLS - 1) crow = NCLS - 1;     // tail tile: clamp (lanes masked at output)
    const float* wrow = W + (size_t)crow * (NF * NDOF);

    float acc[64];
#pragma unroll
    for (int i = 0; i < 64; ++i) acc[i] = 0.0f;
    float rowsum = 0.0f;

    const float* base0 = &w_lds[lane];            // f-slot 0
    const float* base1 = &w_lds[FSTRIDE + lane];  // f-slot 1
    int b0 = wave * 64;

#pragma unroll 1
    for (int chunk = 0; chunk < NCHUNK; ++chunk) {
        int fc = f0 + chunk * FCHUNK;
        __syncthreads();
        // ---- stage W chunk: 64 c x 2 f x 64 p, transposed to [f][p][c] (pad 65)
        {
            const float4* src = (const float4*)(wrow + (size_t)(fc + fl_st) * NDOF + half * 32);
            float* dst = &w_lds[fl_st * FSTRIDE + cst];
#pragma unroll
            for (int q = 0; q < 8; ++q) {
                float4 v = src[q];
                int p = half * 32 + q * 4;
                dst[(p + 0) * 65] = v.x;
                dst[(p + 1) * 65] = v.y;
                dst[(p + 2) * 65] = v.z;
                dst[(p + 3) * 65] = v.w;
                rowsum += (v.x + v.y) + (v.z + v.w);   // for the -min_x * rowsum bias
            }
        }
        __syncthreads();
        // ---- gather-accumulate: per b, wave-uniform meta broadcast + 2x ds_read2
        const float4* mp = &meta4[(size_t)(fc >> 1) * NB + b0];
#pragma unroll
        for (int bl = 0; bl < 64; ++bl) {
            float4 m = mp[bl];                       // 16B broadcast load (L1/L2)
            uint32_t t0 = __float_as_uint(m.x) & 63u;
            uint32_t t1 = __float_as_uint(m.z) & 63u;
            float a0 = base0[t0 * 65];
            float a1 = base0[t0 * 65 + 65];
            float c0v = base1[t1 * 65];
            float c1v = base1[t1 * 65 + 65];
            acc[bl] = fmaf(m.x, a0, fmaf(m.y, a1, acc[bl]));
            acc[bl] = fmaf(m.z, c0v, fmaf(m.w, c1v, acc[bl]));
        }
    }

    // ---- bias: reduce rowsum across the 4 staging threads of each class row
    rowsum += __shfl_xor(rowsum, 1);
    rowsum += __shfl_xor(rowsum, 2);
    float mn = mnp[0];
    if (g == 0) w_lds[WLDS_DW + cst] = mn * rowsum;
    __syncthreads();

    int c = c0 + lane;
    if (c < NCLS) {
        float bias = w_lds[WLDS_DW + lane];
#pragma unroll
        for (int bl = 0; bl < 64; ++bl) {
            atomicAdd(&out[(size_t)(b0 + bl) * NCLS + c], acc[bl] + bias);
        }
    }
}

extern "C" void kernel_launch(void* const* d_in, const int* in_sizes, int n_in,
                              void* d_out, int out_size, void* d_ws, size_t ws_size,
                              hipStream_t stream) {
    const float* x  = (const float*)d_in[0];
    const float* mn = (const float*)d_in[1];
    const float* mx = (const float*)d_in[2];
    const float* W  = (const float*)d_in[3];
    float* out = (float*)d_out;
    float2* meta = (float2*)d_ws;   // NF/2 * NB float4 = 2 MB scratch

    hipMemsetAsync(d_out, 0, (size_t)NB * NCLS * sizeof(float), stream);

    lagr_meta<<<dim3(NF), dim3(NB), 0, stream>>>(x, mn, mx, meta);

    dim3 grid(NF / FGROUP, (NCLS + CTILE - 1) / CTILE);
    lagr_main<<<grid, dim3(256), 0, stream>>>((const float4*)meta, W, mn, out);
}